// Round 8
// baseline (543.393 us; speedup 1.0000x reference)
//
#include <hip/hip_runtime.h>
#include <hip/hip_bf16.h>
#include <cstdint>
#include <cstddef>

#define LRELU_ALPHA 0.2f

typedef __attribute__((ext_vector_type(8))) short short8;
typedef __attribute__((ext_vector_type(4))) float f32x4;

__device__ __forceinline__ unsigned short f2bf(float f) {
    unsigned int u = __float_as_uint(f);
    unsigned int r = (u + 0x7fffu + ((u >> 16) & 1u)) >> 16;   // RTN-even
    return (unsigned short)r;
}
__device__ __forceinline__ float bf2f(unsigned int lo16) {
    return __uint_as_float(lo16 << 16);
}
__device__ __forceinline__ unsigned int pk2(float a, float b) {
    return (unsigned int)f2bf(a) | ((unsigned int)f2bf(b) << 16);
}

// ---------------- fused prep: 4 weight repacks + zero counts + zero scol pad ----------------
// repack: src is HD heads of [128][KJ/HD] fp32 -> wt[n][k] bf16 (n-major over KJ cols)

__device__ __forceinline__ void repack_dev(const float* __restrict__ src,
                                           unsigned short* __restrict__ wt,
                                           int b, int KJ, int JW) {
    int i = b * 256 + threadIdx.x;
    if (i < KJ * 128) {
        int n = i >> 7, k = i & 127;
        int hd = n / JW, j = n % JW;
        wt[i] = f2bf(src[(hd * 128 + k) * JW + j]);
    }
}

__global__ void prep_k(const float* __restrict__ Win, const float* __restrict__ Whid,
                       const float* __restrict__ Wout,
                       unsigned short* __restrict__ WT0, unsigned short* __restrict__ WT1,
                       unsigned short* __restrict__ WT2, unsigned short* __restrict__ WT3,
                       int* __restrict__ counts, int* __restrict__ scol,
                       int n, int E_, int nb) {
    int b = blockIdx.x;
    if (b < 64)       repack_dev(Win, WT0, b, 128, 128);
    else if (b < 128) repack_dev(Whid, WT1, b - 64, 128, 32);
    else if (b < 192) repack_dev(Whid + 4 * 128 * 32, WT2, b - 128, 128, 32);
    else if (b < 224) repack_dev(Wout, WT3, b - 192, 64, 64);
    else if (b < 224 + nb) {
        int i = (b - 224) * 256 + threadIdx.x;
        if (i < n) counts[i] = 0;
    } else {
        scol[E_ + threadIdx.x] = 0;   // sentinel pad (256 entries)
    }
}

// ---------------- CSR build ----------------

__global__ void hist_k(const int* __restrict__ ei, int* __restrict__ counts,
                       int* __restrict__ rank, int E2) {
    int e2 = blockIdx.x * 256 + threadIdx.x;
    if (e2 < E2) {
        int2 rr = *(const int2*)&ei[e2 * 2];
        int2 rk;
        rk.x = atomicAdd(&counts[rr.x], 1);
        rk.y = atomicAdd(&counts[rr.y], 1);
        *(int2*)&rank[e2 * 2] = rk;
    }
}

__global__ void scan_block_k(const int* __restrict__ counts, int* __restrict__ tmp,
                             int* __restrict__ bsum, int n) {
    __shared__ int s[256];
    int i = blockIdx.x * 256 + threadIdx.x;
    int v = (i < n) ? counts[i] : 0;
    s[threadIdx.x] = v;
    __syncthreads();
    for (int d = 1; d < 256; d <<= 1) {
        int t_ = (threadIdx.x >= d) ? s[threadIdx.x - d] : 0;
        __syncthreads();
        s[threadIdx.x] += t_;
        __syncthreads();
    }
    if (i < n) tmp[i] = s[threadIdx.x];
    if (threadIdx.x == 255) bsum[blockIdx.x] = s[255];
}

__global__ void scan_sums_k(int* bsum, int nb) {
    __shared__ int s[512];
    int v = ((int)threadIdx.x < nb) ? bsum[threadIdx.x] : 0;
    s[threadIdx.x] = v;
    __syncthreads();
    for (int d = 1; d < 512; d <<= 1) {
        int t_ = ((int)threadIdx.x >= d) ? s[threadIdx.x - d] : 0;
        __syncthreads();
        s[threadIdx.x] += t_;
        __syncthreads();
    }
    if ((int)threadIdx.x < nb) bsum[threadIdx.x] = s[threadIdx.x] - v;  // exclusive
}

__global__ void finalize_k(const int* __restrict__ tmp, const int* __restrict__ bsum,
                           int* __restrict__ off, int n) {
    int i = blockIdx.x * 256 + threadIdx.x;
    if (i < n) off[i + 1] = tmp[i] + bsum[blockIdx.x];
    if (i == 0) off[0] = 0;
}

__global__ void scatter_k(const int* __restrict__ ei, const int* __restrict__ rank,
                          const int* __restrict__ off, int* __restrict__ scol, int E2) {
    int e2 = blockIdx.x * 256 + threadIdx.x;
    if (e2 < E2) {
        int2 rr = *(const int2*)&ei[e2 * 2];
        int2 rk = *(const int2*)&rank[e2 * 2];
        int2 cc = *(const int2*)&ei[E2 * 2 + e2 * 2];
        scol[off[rr.x] + rk.x] = cc.x;
        scol[off[rr.y] + rk.y] = cc.y;
    }
}

// ---------------- MFMA GEMM: Y[n, 0:KJ] = act(X[n,0:128] @ W[128,KJ] + bias) -------------

template <int KJ, bool ELU_ACT, bool BIAS, bool BF16_OUT, bool ABF16>
__global__ __launch_bounds__(256) void gemm_mfma(const void* __restrict__ Xv,
                                                 const unsigned short* __restrict__ WT,
                                                 const float* __restrict__ bias,
                                                 void* __restrict__ Yv, int nRows) {
    constexpr int NT = KJ / 16;
    constexpr int WS = 136;
    __shared__ unsigned short sWT[KJ * WS];
    int t = threadIdx.x;
    for (int i = t; i < KJ * 16; i += 256) {
        int n = i >> 4, k8 = i & 15;
        uint4 v = *(const uint4*)&WT[n * 128 + k8 * 8];
        *(uint4*)&sWT[n * WS + k8 * 8] = v;
    }
    __syncthreads();

    int lane = t & 63;
    int wv = t >> 6;
    int m0 = blockIdx.x * 128 + wv * 32;
    int l16 = lane & 15;
    int q4 = lane >> 4;

    short8 afr[4][2];
    #pragma unroll
    for (int rt = 0; rt < 2; rt++) {
        int row = m0 + rt * 16 + l16;
        bool vr = row < nRows;
        if (ABF16) {
            const unsigned int* xp = (const unsigned int*)Xv + (size_t)row * 64 + q4 * 4;
            #pragma unroll
            for (int kk = 0; kk < 4; kk++) {
                uint4 u = make_uint4(0u, 0u, 0u, 0u);
                if (vr) u = *(const uint4*)(xp + kk * 16);
                afr[kk][rt] = *(short8*)&u;
            }
        } else {
            const float* xp = (const float*)Xv + (size_t)row * 128 + q4 * 8;
            #pragma unroll
            for (int kk = 0; kk < 4; kk++) {
                float4 a0 = make_float4(0.f, 0.f, 0.f, 0.f), a1 = a0;
                if (vr) {
                    a0 = *(const float4*)(xp + kk * 32);
                    a1 = *(const float4*)(xp + kk * 32 + 4);
                }
                unsigned int u[4];
                u[0] = pk2(a0.x, a0.y); u[1] = pk2(a0.z, a0.w);
                u[2] = pk2(a1.x, a1.y); u[3] = pk2(a1.z, a1.w);
                afr[kk][rt] = *(short8*)u;
            }
        }
    }

    f32x4 acc[2][NT] = {};
    #pragma unroll
    for (int kk = 0; kk < 4; kk++) {
        #pragma unroll
        for (int ct = 0; ct < NT; ct++) {
            int n = ct * 16 + l16;
            short8 bf = *(const short8*)&sWT[n * WS + kk * 32 + q4 * 8];
            #pragma unroll
            for (int rt = 0; rt < 2; rt++)
                acc[rt][ct] = __builtin_amdgcn_mfma_f32_16x16x32_bf16(afr[kk][rt], bf, acc[rt][ct], 0, 0, 0);
        }
    }

    #pragma unroll
    for (int rt = 0; rt < 2; rt++) {
        #pragma unroll
        for (int q = 0; q < 4; q++) {
            int row = m0 + rt * 16 + q4 * 4 + q;
            if (row >= nRows) continue;
            #pragma unroll
            for (int ct = 0; ct < NT; ct++) {
                int colc = ct * 16 + l16;
                float v = acc[rt][ct][q];
                if (BIAS) v += bias[colc];
                if (ELU_ACT) v = v > 0.f ? v : (__expf(v) - 1.f);
                if (BF16_OUT) ((unsigned short*)Yv)[(size_t)row * KJ + colc] = f2bf(v);
                else          ((float*)Yv)[(size_t)row * KJ + colc] = v;
            }
        }
    }
}

// ---------------- layer-0 attention scores; writes interleaved sAB[node][hd][src|dst] ------

__global__ __launch_bounds__(256) void attn0_bf(const unsigned int* __restrict__ h2,
                                                const float* __restrict__ a,
                                                float* __restrict__ sAB, int n) {
    __shared__ float sa[8 * 128];
    for (int i = threadIdx.x; i < 8 * 128; i += 256) sa[i] = a[i];
    __syncthreads();
    int lane = threadIdx.x & 63, wv = threadIdx.x >> 6;
    int node = blockIdx.x * 4 + wv;
    if (node >= n) return;
    unsigned int hv = h2[(size_t)node * 64 + lane];
    float v0 = bf2f(hv & 0xffffu), v1 = bf2f(hv >> 16);
    #pragma unroll
    for (int hd = 0; hd < 4; hd++) {
        #pragma unroll
        for (int side = 0; side < 2; side++) {
            const float2 aa = *(const float2*)&sa[(hd * 2 + side) * 128 + 2 * lane];
            float p = v0 * aa.x + v1 * aa.y;
            #pragma unroll
            for (int s = 32; s > 0; s >>= 1) p += __shfl_xor(p, s);
            if (lane == 0) sAB[node * 8 + hd * 2 + side] = p;
        }
    }
}

// ---------------- edge pass: 2 rows per wave, bf16 hW, fused next-layer scores -------------
// Per row: 32 lanes = 2 slots (g) x 16 subs; each iter handles 4 edges/row (2 per slot).
// Wave-uniform trip = max over the two rows; out-of-row loads hit the zero-padded scol
// (valid indices) with w=0. lrelu via fmaxf(x, 0.2x). No softmax max-pass (|logit| small).
// Scores interleaved: sAB[node*2H + head*2 + (0=src,1=dst)].

template <int DHT, int H, bool ELU_ACT, int HN, bool BF16O>
__global__ __launch_bounds__(256) void edge_agg2r(const unsigned int* __restrict__ hW2,
                                                  const float* __restrict__ sAB,
                                                  const int* __restrict__ off,
                                                  const int* __restrict__ scol,
                                                  void* __restrict__ outv,
                                                  const float* __restrict__ a_next,
                                                  float* __restrict__ sABn, int nRows) {
    constexpr int FPL = DHT / 16;   // features per lane: 8 or 4
    constexpr int UPL = FPL / 2;    // packed uints per lane: 4 or 2
    constexpr int NC = (HN > 0) ? 2 * HN : 1;
    __shared__ float sAN[NC * 128];
    if (HN > 0) {
        for (int i = threadIdx.x; i < NC * 128; i += 256) sAN[i] = a_next[i];
        __syncthreads();
    }
    int lane = threadIdx.x & 63;
    int sub = lane & 15;
    int g = (lane >> 4) & 1;
    int half = lane >> 5;
    int wv = threadIdx.x >> 6;
    int row = blockIdx.x * 8 + wv * 2 + half;
    bool vrow = row < nRows;
    int rowc = vrow ? row : 0;
    int begin = off[rowc];
    int end = vrow ? off[rowc + 1] : begin;

    int head = (H == 4) ? (sub >> 2) : 0;
    float ssl = sAB[rowc * 2 * H + head * 2];

    int iters = (end - begin + 3) >> 2;
    int o = __shfl_xor(iters, 32);
    int itmax = iters > o ? iters : o;

    float acc[FPL] = {};
    float den = 0.f;
    int idx0 = begin + g * 2;

    for (int k = 0; k < itmax; k++) {
        int iA = idx0 + k * 4, iB = iA + 1;
        int cA = scol[iA];
        int cB = scol[iB];
        float sdA = sAB[cA * 2 * H + head * 2 + 1];
        float sdB = sAB[cB * 2 * H + head * 2 + 1];
        unsigned int hA[UPL], hB[UPL];
        if (UPL == 4) {
            *(uint4*)hA = *(const uint4*)&hW2[(size_t)cA * 64 + sub * 4];
            *(uint4*)hB = *(const uint4*)&hW2[(size_t)cB * 64 + sub * 4];
        } else {
            *(uint2*)hA = *(const uint2*)&hW2[(size_t)cA * 32 + sub * 2];
            *(uint2*)hB = *(const uint2*)&hW2[(size_t)cB * 32 + sub * 2];
        }
        float lgA = ssl + sdA; lgA = fmaxf(lgA, LRELU_ALPHA * lgA);
        float wA = (iA < end) ? __expf(lgA) : 0.f;
        float lgB = ssl + sdB; lgB = fmaxf(lgB, LRELU_ALPHA * lgB);
        float wB = (iB < end) ? __expf(lgB) : 0.f;
        den += wA + wB;
        #pragma unroll
        for (int q = 0; q < UPL; q++) {
            acc[2 * q]     = fmaf(wA, bf2f(hA[q] & 0xffffu), acc[2 * q]);
            acc[2 * q + 1] = fmaf(wA, bf2f(hA[q] >> 16),     acc[2 * q + 1]);
            acc[2 * q]     = fmaf(wB, bf2f(hB[q] & 0xffffu), acc[2 * q]);
            acc[2 * q + 1] = fmaf(wB, bf2f(hB[q] >> 16),     acc[2 * q + 1]);
        }
    }

    // combine the 2 slots (within each 32-lane half)
    den += __shfl_xor(den, 16);
    #pragma unroll
    for (int p = 0; p < FPL; p++) acc[p] += __shfl_xor(acc[p], 16);
    float inv = den > 0.f ? 1.f / den : 0.f;

    float v[FPL];
    #pragma unroll
    for (int p = 0; p < FPL; p++) {
        float tv = acc[p] * inv;
        if (ELU_ACT) tv = tv > 0.f ? tv : (__expf(tv) - 1.f);
        v[p] = tv;
    }

    if (DHT == 128) {
        if (vrow && g == 0) {
            unsigned int pk[4];
            #pragma unroll
            for (int q = 0; q < 4; q++) pk[q] = pk2(v[2 * q], v[2 * q + 1]);
            if (BF16O)
                *(uint4*)&((unsigned int*)outv)[(size_t)row * 64 + sub * 4] = *(uint4*)pk;
            else {
                float4 f0 = make_float4(v[0], v[1], v[2], v[3]);
                float4 f1 = make_float4(v[4], v[5], v[6], v[7]);
                *(float4*)&((float*)outv)[(size_t)row * 128 + sub * 8] = f0;
                *(float4*)&((float*)outv)[(size_t)row * 128 + sub * 8 + 4] = f1;
            }
        }
    } else {
        if (vrow && g == 0)
            *(float4*)&((float*)outv)[(size_t)row * 64 + sub * 4] =
                make_float4(v[0], v[1], v[2], v[3]);
    }

    if (HN > 0) {
        if (HN == 4) {
            float part[4];
            #pragma unroll
            for (int cc = 0; cc < 4; cc++) {
                int ch = g * 4 + cc;
                const float* ap = &sAN[ch * 128 + sub * FPL];
                float pa = 0.f;
                #pragma unroll
                for (int p = 0; p < FPL; p++) pa += v[p] * ap[p];
                #pragma unroll
                for (int s = 1; s < 16; s <<= 1) pa += __shfl_xor(pa, s);
                part[cc] = pa;
            }
            if (vrow && sub == 0)
                *(float4*)&sABn[(size_t)row * 8 + g * 4] =
                    make_float4(part[0], part[1], part[2], part[3]);
        } else {
            const float* ap = &sAN[g * 128 + sub * FPL];
            float pa = 0.f;
            #pragma unroll
            for (int p = 0; p < FPL; p++) pa += v[p] * ap[p];
            #pragma unroll
            for (int s = 1; s < 16; s <<= 1) pa += __shfl_xor(pa, s);
            if (vrow && sub == 0) sABn[(size_t)row * 2 + g] = pa;
        }
    }
}

// ---------------- launcher ----------------

extern "C" void kernel_launch(void* const* d_in, const int* in_sizes, int n_in,
                              void* d_out, int out_size, void* d_ws, size_t ws_size,
                              hipStream_t stream) {
    const float* x    = (const float*)d_in[0];
    const int*   ei   = (const int*)d_in[1];
    const float* Win  = (const float*)d_in[2];
    const float* bin  = (const float*)d_in[3];
    const float* ahid = (const float*)d_in[4];
    const float* Whid = (const float*)d_in[5];
    const float* aout = (const float*)d_in[6];
    const float* Wout = (const float*)d_in[7];
    float* out = (float*)d_out;

    const int N_ = in_sizes[0] / 128;
    const int E_ = in_sizes[1] / 2;
    const int E2 = E_ / 2;

    char* p = (char*)d_ws;
    auto alloc = [&](size_t bytes) {
        char* q = p;
        p += (bytes + 511) & ~(size_t)511;
        return q;
    };
    int* counts = (int*)alloc((size_t)N_ * 4);
    int* tmp    = (int*)alloc((size_t)N_ * 4);
    int* rank   = (int*)alloc((size_t)E_ * 4);
    int* off    = (int*)alloc((size_t)(N_ + 1) * 4);
    int* bsum   = (int*)alloc(4096);
    int* scol   = (int*)alloc((size_t)(E_ + 256) * 4);
    float* sABa = (float*)alloc((size_t)N_ * 8 * 4);
    float* sABb = (float*)alloc((size_t)N_ * 8 * 4);
    unsigned int* hb  = (unsigned int*)alloc((size_t)N_ * 64 * 4);   // h  bf16 packed
    unsigned int* hWb = (unsigned int*)alloc((size_t)N_ * 64 * 4);   // hW bf16 packed
    unsigned short* WT0 = (unsigned short*)alloc(128 * 128 * 2);
    unsigned short* WT1 = (unsigned short*)alloc(128 * 128 * 2);
    unsigned short* WT2 = (unsigned short*)alloc(128 * 128 * 2);
    unsigned short* WT3 = (unsigned short*)alloc(64 * 128 * 2);

    int NB = (N_ + 255) / 256;
    int EB2 = (E2 + 255) / 256;
    int RT = (N_ + 127) / 128;
    int NW4 = (N_ + 3) / 4;
    int NW8 = (N_ + 7) / 8;

    // prep: weight repacks + zero counts + scol sentinel pad
    prep_k<<<224 + NB + 1, 256, 0, stream>>>(Win, Whid, Wout, WT0, WT1, WT2, WT3,
                                             counts, scol, N_, E_, NB);

    // CSR by destination (= edge_index[0], the softmax segment key)
    hist_k<<<EB2, 256, 0, stream>>>(ei, counts, rank, E2);
    scan_block_k<<<NB, 256, 0, stream>>>(counts, tmp, bsum, N_);
    scan_sums_k<<<1, 512, 0, stream>>>(bsum, NB);
    finalize_k<<<NB, 256, 0, stream>>>(tmp, bsum, off, N_);
    scatter_k<<<EB2, 256, 0, stream>>>(ei, rank, off, scol, E2);

    // input linear + ELU -> h0 bf16
    gemm_mfma<128, true, true, true, false><<<RT, 256, 0, stream>>>(x, WT0, bin, hb, N_);

    // layer-0 attention scores
    attn0_bf<<<NW4, 256, 0, stream>>>(hb, ahid, sABa, N_);

    // hidden layer 1
    gemm_mfma<128, false, false, true, true><<<RT, 256, 0, stream>>>(hb, WT1, nullptr, hWb, N_);
    edge_agg2r<128, 4, true, 4, true><<<NW8, 256, 0, stream>>>(
        hWb, sABa, off, scol, hb, ahid + 4 * 2 * 128, sABb, N_);

    // hidden layer 2
    gemm_mfma<128, false, false, true, true><<<RT, 256, 0, stream>>>(hb, WT2, nullptr, hWb, N_);
    edge_agg2r<128, 4, true, 1, true><<<NW8, 256, 0, stream>>>(
        hWb, sABb, off, scol, hb, aout, sABa, N_);

    // output layer
    gemm_mfma<64, false, false, true, true><<<RT, 256, 0, stream>>>(hb, WT3, nullptr, hWb, N_);
    edge_agg2r<64, 1, false, 0, false><<<NW8, 256, 0, stream>>>(
        hWb, sABa, off, scol, out, nullptr, nullptr, N_);
}